// Round 1
// baseline (351.928 us; speedup 1.0000x reference)
//
#include <hip/hip_runtime.h>
#include <stdint.h>

typedef __bf16 bf16;
typedef bf16 bf16x8 __attribute__((ext_vector_type(8)));
typedef bf16 bf16x4 __attribute__((ext_vector_type(4)));
typedef float f32x4 __attribute__((ext_vector_type(4)));

constexpr int B_ = 2, L_ = 2048, D_ = 1024, H_ = 16, DH_ = 64;
constexpr int M_ = B_ * L_;      // 4096 rows
constexpr float SCALE = 0.125f;  // 1/sqrt(64)

__device__ __forceinline__ void gload_lds16(const void* g, void* l) {
  __builtin_amdgcn_global_load_lds(
      (const __attribute__((address_space(1))) unsigned int*)g,
      (__attribute__((address_space(3))) unsigned int*)l, 16, 0, 0);
}

// ---------------- cast fp32 -> bf16 (vectorized) ----------------
__global__ void cast_f32_to_bf16(const float* __restrict__ src,
                                 bf16* __restrict__ dst, int n4) {
  int i = blockIdx.x * blockDim.x + threadIdx.x;
  if (i >= n4) return;
  float4 v = reinterpret_cast<const float4*>(src)[i];
  bf16x4 o;
  o[0] = (bf16)v.x; o[1] = (bf16)v.y; o[2] = (bf16)v.z; o[3] = (bf16)v.w;
  reinterpret_cast<bf16x4*>(dst)[i] = o;
}

// ---------------- weight transpose + cast: W[K][N] -> Wt[N][K] ----------------
__global__ void transpose_cast_w(const float* __restrict__ W, bf16* __restrict__ Wt) {
  __shared__ float tile[32][33];
  int tx = threadIdx.x, ty = threadIdx.y;          // 32 x 8
  int r0 = blockIdx.y * 32, c0 = blockIdx.x * 32;  // r over K(in), c over N(out)
#pragma unroll
  for (int i = 0; i < 32; i += 8)
    tile[ty + i][tx] = W[(size_t)(r0 + ty + i) * D_ + c0 + tx];
  __syncthreads();
#pragma unroll
  for (int i = 0; i < 32; i += 8)
    Wt[(size_t)(c0 + ty + i) * D_ + r0 + tx] = (bf16)tile[tx][ty + i];
}

// ---------------- GEMM: C[M][N] = A[M][K] * Bt[N][K]^T + bias ----------------
// MODE 0: write bf16 to [B,H,L,DH]   (Q, K projections)
// MODE 1: write bf16 to [B,H,DH,L]   (V projection, transposed)
// MODE 2: write fp32 to [M][N]       (output projection)
constexpr int BM = 128, BN = 64, BK = 32;

template <int MODE>
__global__ __launch_bounds__(256) void gemm_bf16(
    const bf16* __restrict__ A, const bf16* __restrict__ Bt,
    const float* __restrict__ bias, void* __restrict__ outp) {
  __shared__ bf16 As[BM * BK];  // linear [128][32]
  __shared__ bf16 Bs[BN * BK];  // linear [64][32]
  const int tid = threadIdx.x;
  const int wid = tid >> 6, lane = tid & 63;
  const int lr = lane & 15, lg = lane >> 4;
  const int wr = wid >> 1, wc = wid & 1;  // 2x2 waves, wave tile 64x32
  const int m0 = blockIdx.y * BM, n0 = blockIdx.x * BN;

  f32x4 acc[4][2] = {};

  for (int kt = 0; kt < D_; kt += BK) {
    __syncthreads();
    // stage A tile: 8KB = 512 x 16B chunks, 2 issues per wave
#pragma unroll
    for (int i = 0; i < 2; ++i) {
      int c = (i * 4 + wid) * 64 + lane;
      int row = c >> 2, cs = c & 3;
      gload_lds16(A + (size_t)(m0 + row) * D_ + kt + cs * 8,
                  (char*)As + (i * 4 + wid) * 1024);
    }
    // stage B tile: 4KB = 256 chunks, 1 issue per wave
    {
      int c = wid * 64 + lane;
      int row = c >> 2, cs = c & 3;
      gload_lds16(Bt + (size_t)(n0 + row) * D_ + kt + cs * 8,
                  (char*)Bs + wid * 1024);
    }
    __syncthreads();

    bf16x8 af[4], bfr[2];
#pragma unroll
    for (int i = 0; i < 4; ++i)
      af[i] = *(const bf16x8*)(As + (wr * 64 + i * 16 + lr) * BK + lg * 8);
#pragma unroll
    for (int j = 0; j < 2; ++j)
      bfr[j] = *(const bf16x8*)(Bs + (wc * 32 + j * 16 + lr) * BK + lg * 8);
#pragma unroll
    for (int i = 0; i < 4; ++i)
#pragma unroll
      for (int j = 0; j < 2; ++j)
        acc[i][j] = __builtin_amdgcn_mfma_f32_16x16x32_bf16(af[i], bfr[j], acc[i][j], 0, 0, 0);
  }

  // epilogue: C/D layout col = lane&15, row = (lane>>4)*4 + r  [m89-verified]
#pragma unroll
  for (int i = 0; i < 4; ++i) {
#pragma unroll
    for (int j = 0; j < 2; ++j) {
      const int n = n0 + wc * 32 + j * 16 + lr;
      const float bn = bias[n];
      const int mbase = m0 + wr * 64 + i * 16 + lg * 4;
      if constexpr (MODE == 2) {
        float* out = (float*)outp;
#pragma unroll
        for (int r = 0; r < 4; ++r)
          out[(size_t)(mbase + r) * D_ + n] = acc[i][j][r] + bn;
      } else if constexpr (MODE == 0) {
        bf16* out = (bf16*)outp;
        const int h = n >> 6, dh = n & 63;
#pragma unroll
        for (int r = 0; r < 4; ++r) {
          int m = mbase + r;
          int b = m >> 11, l = m & (L_ - 1);
          out[((size_t)(b * H_ + h) * L_ + l) * DH_ + dh] = (bf16)(acc[i][j][r] + bn);
        }
      } else {  // MODE 1: Vt[b][h][dh][l], 4 consecutive l per lane -> 8B store
        bf16* out = (bf16*)outp;
        const int h = n >> 6, dh = n & 63;
        int b = mbase >> 11, l = mbase & (L_ - 1);
        bf16x4 pk;
#pragma unroll
        for (int r = 0; r < 4; ++r) pk[r] = (bf16)(acc[i][j][r] + bn);
        *(bf16x4*)(out + ((size_t)(b * H_ + h) * DH_ + dh) * L_ + l) = pk;
      }
    }
  }
}

// ---------------- flash attention (causal) ----------------
// grid: (L/64, H, B). Block: 4 waves; wave w owns q-rows [qt*64+w*16, +16).
__global__ __launch_bounds__(256) void attn_fwd(
    const bf16* __restrict__ Q,   // [B,H,L,DH]
    const bf16* __restrict__ K,   // [B,H,L,DH]
    const bf16* __restrict__ Vt,  // [B,H,DH,L]
    bf16* __restrict__ O) {       // [B,L,D]
  __shared__ bf16 Ks[64 * 64];        // XOR-swizzled within each 128B row
  __shared__ bf16 Vs[64 * 64];        // XOR-swizzled
  __shared__ bf16 Ps[4][16 * 72];     // per-wave P strip, padded stride 72
  const int tid = threadIdx.x;
  const int wid = tid >> 6, lane = tid & 63;
  const int lr = lane & 15, lg = lane >> 4;
  const int qt = (gridDim.x - 1) - blockIdx.x;  // heavy tiles first
  const int h = blockIdx.y, b = blockIdx.z;
  const size_t bh = (size_t)b * H_ + h;

  // Q fragments held in registers for the whole kernel
  const bf16* qbase = Q + (bh * L_ + (size_t)qt * 64 + wid * 16) * DH_;
  bf16x8 qf[2];
#pragma unroll
  for (int kk = 0; kk < 2; ++kk)
    qf[kk] = *(const bf16x8*)(qbase + lr * DH_ + kk * 32 + lg * 8);

  f32x4 oacc[4] = {};
  float mrun[4], lrun[4];
#pragma unroll
  for (int r = 0; r < 4; ++r) { mrun[r] = -3.0e38f; lrun[r] = 0.f; }
  const int qrow = qt * 64 + wid * 16 + lg * 4;  // + r

  for (int kt = 0; kt <= qt; ++kt) {
    __syncthreads();
    // stage K tile (8KB contiguous) and Vt tile; swizzle via per-lane global src
#pragma unroll
    for (int i = 0; i < 2; ++i) {
      int c = (i * 4 + wid) * 64 + lane;
      int row = c >> 3, cs = c & 7, g = cs ^ (row & 7);
      gload_lds16(K + (bh * L_ + (size_t)kt * 64 + row) * DH_ + g * 8,
                  (char*)Ks + (i * 4 + wid) * 1024);
      gload_lds16(Vt + (bh * DH_ + row) * L_ + (size_t)kt * 64 + g * 8,
                  (char*)Vs + (i * 4 + wid) * 1024);
    }
    __syncthreads();

    // S = Q K^T strip (16 x 64)
    f32x4 s[4] = {};
#pragma unroll
    for (int kk = 0; kk < 2; ++kk)
#pragma unroll
      for (int j = 0; j < 4; ++j) {
        int key = j * 16 + lr;
        int ch = kk * 4 + lg;
        bf16x8 bk = *(const bf16x8*)((char*)Ks + key * 128 + ((ch ^ (key & 7)) << 4));
        s[j] = __builtin_amdgcn_mfma_f32_16x16x32_bf16(qf[kk], bk, s[j], 0, 0, 0);
      }

    // scale + causal mask (only the diagonal tile has masked entries)
    if (kt == qt) {
#pragma unroll
      for (int j = 0; j < 4; ++j) {
        int key = kt * 64 + j * 16 + lr;
#pragma unroll
        for (int r = 0; r < 4; ++r)
          s[j][r] = (key > qrow + r) ? -3.0e38f : s[j][r] * SCALE;
      }
    } else {
#pragma unroll
      for (int j = 0; j < 4; ++j)
#pragma unroll
        for (int r = 0; r < 4; ++r) s[j][r] *= SCALE;
    }

    // online softmax: row-reduce across 16 lanes (rows live in lane>>4 groups)
    float t[4];
#pragma unroll
    for (int r = 0; r < 4; ++r)
      t[r] = fmaxf(fmaxf(s[0][r], s[1][r]), fmaxf(s[2][r], s[3][r]));
#pragma unroll
    for (int d = 1; d < 16; d <<= 1)
#pragma unroll
      for (int r = 0; r < 4; ++r) t[r] = fmaxf(t[r], __shfl_xor(t[r], d));

    float corr[4];
#pragma unroll
    for (int r = 0; r < 4; ++r) {
      float mn = fmaxf(mrun[r], t[r]);
      corr[r] = __expf(mrun[r] - mn);
      mrun[r] = mn;
    }
    float rs[4] = {0.f, 0.f, 0.f, 0.f};
#pragma unroll
    for (int j = 0; j < 4; ++j)
#pragma unroll
      for (int r = 0; r < 4; ++r) {
        float p = __expf(s[j][r] - mrun[r]);
        s[j][r] = p;
        rs[r] += p;
      }
#pragma unroll
    for (int d = 1; d < 16; d <<= 1)
#pragma unroll
      for (int r = 0; r < 4; ++r) rs[r] += __shfl_xor(rs[r], d);
#pragma unroll
    for (int r = 0; r < 4; ++r) lrun[r] = lrun[r] * corr[r] + rs[r];
#pragma unroll
    for (int j = 0; j < 4; ++j)
#pragma unroll
      for (int r = 0; r < 4; ++r) oacc[j][r] *= corr[r];

    // P -> per-wave LDS (bf16), then PV MFMA
    bf16* pw = &Ps[wid][0];
#pragma unroll
    for (int j = 0; j < 4; ++j)
#pragma unroll
      for (int r = 0; r < 4; ++r)
        pw[(lg * 4 + r) * 72 + j * 16 + lr] = (bf16)s[j][r];

    bf16x8 ap[2];
#pragma unroll
    for (int st = 0; st < 2; ++st)
      ap[st] = *(const bf16x8*)(pw + lr * 72 + st * 32 + lg * 8);
#pragma unroll
    for (int j = 0; j < 4; ++j)
#pragma unroll
      for (int st = 0; st < 2; ++st) {
        int dh = j * 16 + lr;
        int ch = st * 4 + lg;
        bf16x8 bv = *(const bf16x8*)((char*)Vs + dh * 128 + ((ch ^ (dh & 7)) << 4));
        oacc[j] = __builtin_amdgcn_mfma_f32_16x16x32_bf16(ap[st], bv, oacc[j], 0, 0, 0);
      }
  }

  // epilogue: O[b][q][h*64+dh] = oacc / l
#pragma unroll
  for (int j = 0; j < 4; ++j) {
#pragma unroll
    for (int r = 0; r < 4; ++r) {
      int q = qrow + r;
      int dh = j * 16 + lr;
      O[((size_t)b * L_ + q) * D_ + h * DH_ + dh] = (bf16)(oacc[j][r] / lrun[r]);
    }
  }
}

// ---------------- launcher ----------------
extern "C" void kernel_launch(void* const* d_in, const int* in_sizes, int n_in,
                              void* d_out, int out_size, void* d_ws, size_t ws_size,
                              hipStream_t stream) {
  const float* q  = (const float*)d_in[0];
  const float* k  = (const float*)d_in[1];
  const float* v  = (const float*)d_in[2];
  // d_in[3] is the causal mask; causality is computed from indices instead.
  const float* Wq = (const float*)d_in[4];
  const float* bq = (const float*)d_in[5];
  const float* Wk = (const float*)d_in[6];
  const float* bk = (const float*)d_in[7];
  const float* Wv = (const float*)d_in[8];
  const float* bv = (const float*)d_in[9];
  const float* Wo = (const float*)d_in[10];
  const float* bo = (const float*)d_in[11];

  char* ws = (char*)d_ws;
  bf16* castbuf = (bf16*)(ws);                  // 8 MB; reused as attention output O
  bf16* WqT = (bf16*)(ws + (8ull << 20));
  bf16* WkT = (bf16*)(ws + (10ull << 20));
  bf16* WvT = (bf16*)(ws + (12ull << 20));
  bf16* WoT = (bf16*)(ws + (14ull << 20));
  bf16* Qb  = (bf16*)(ws + (16ull << 20));      // [B,H,L,DH]
  bf16* Kb  = (bf16*)(ws + (24ull << 20));      // [B,H,L,DH]
  bf16* Vtb = (bf16*)(ws + (32ull << 20));      // [B,H,DH,L]; total 40 MB

  dim3 tb(32, 8), tg(D_ / 32, D_ / 32);
  transpose_cast_w<<<tg, tb, 0, stream>>>(Wq, WqT);
  transpose_cast_w<<<tg, tb, 0, stream>>>(Wk, WkT);
  transpose_cast_w<<<tg, tb, 0, stream>>>(Wv, WvT);
  transpose_cast_w<<<tg, tb, 0, stream>>>(Wo, WoT);

  const int n4 = (M_ * D_) / 4;
  dim3 cg((n4 + 255) / 256);
  dim3 gg(D_ / BN, M_ / BM);  // (16, 32)

  cast_f32_to_bf16<<<cg, 256, 0, stream>>>(q, castbuf, n4);
  gemm_bf16<0><<<gg, 256, 0, stream>>>(castbuf, WqT, bq, Qb);
  cast_f32_to_bf16<<<cg, 256, 0, stream>>>(k, castbuf, n4);
  gemm_bf16<0><<<gg, 256, 0, stream>>>(castbuf, WkT, bk, Kb);
  cast_f32_to_bf16<<<cg, 256, 0, stream>>>(v, castbuf, n4);
  gemm_bf16<1><<<gg, 256, 0, stream>>>(castbuf, WvT, bv, Vtb);

  dim3 ag(L_ / 64, H_, B_);  // (32, 16, 2)
  attn_fwd<<<ag, 256, 0, stream>>>(Qb, Kb, Vtb, castbuf);

  gemm_bf16<2><<<gg, 256, 0, stream>>>(castbuf, WoT, bo, (float*)d_out);
}

// Round 3
// 286.289 us; speedup vs baseline: 1.2293x; 1.2293x over previous
//
#include <hip/hip_runtime.h>
#include <stdint.h>

typedef __bf16 bf16;
typedef bf16 bf16x8 __attribute__((ext_vector_type(8)));
typedef bf16 bf16x4 __attribute__((ext_vector_type(4)));
typedef float f32x4 __attribute__((ext_vector_type(4)));

constexpr int B_ = 2, L_ = 2048, D_ = 1024, H_ = 16, DH_ = 64;
constexpr int M_ = B_ * L_;                       // 4096
constexpr float QSCALE = 0.125f * 1.44269504f;    // softmax scale * log2(e), folded into Q

__device__ __forceinline__ void gload_lds16(const void* g, void* l) {
  __builtin_amdgcn_global_load_lds(
      (const __attribute__((address_space(1))) unsigned int*)g,
      (__attribute__((address_space(3))) unsigned int*)l, 16, 0, 0);
}
#define MEMBAR() asm volatile("" ::: "memory")
__device__ __forceinline__ void block_bar() {
  MEMBAR(); __builtin_amdgcn_s_barrier(); MEMBAR();
}

// ---------------- fused cast fp32 -> bf16 for q,k,v ----------------
__global__ void cast3(const float* __restrict__ q, const float* __restrict__ k,
                      const float* __restrict__ v, bf16* __restrict__ dst) {
  const float* src = blockIdx.y == 0 ? q : (blockIdx.y == 1 ? k : v);
  size_t i = (size_t)blockIdx.x * blockDim.x + threadIdx.x;
  float4 val = reinterpret_cast<const float4*>(src)[i];
  bf16x4 o;
  o[0] = (bf16)val.x; o[1] = (bf16)val.y; o[2] = (bf16)val.z; o[3] = (bf16)val.w;
  reinterpret_cast<bf16x4*>(dst + (size_t)blockIdx.y * M_ * D_)[i] = o;
}

// ---------------- batched weight transpose+cast: W[K][N] -> WT[z][N][K] ----------------
__global__ void transpose_cast_w(const float* __restrict__ W0, const float* __restrict__ W1,
                                 const float* __restrict__ W2, const float* __restrict__ W3,
                                 bf16* __restrict__ WT) {
  __shared__ float tile[32][33];
  const float* W = blockIdx.z == 0 ? W0 : blockIdx.z == 1 ? W1 : blockIdx.z == 2 ? W2 : W3;
  bf16* Wt = WT + (size_t)blockIdx.z * D_ * D_;
  int tx = threadIdx.x, ty = threadIdx.y;          // 32 x 8
  int r0 = blockIdx.y * 32, c0 = blockIdx.x * 32;
#pragma unroll
  for (int i = 0; i < 32; i += 8)
    tile[ty + i][tx] = W[(size_t)(r0 + ty + i) * D_ + c0 + tx];
  __syncthreads();
#pragma unroll
  for (int i = 0; i < 32; i += 8)
    Wt[(size_t)(c0 + ty + i) * D_ + r0 + tx] = (bf16)tile[tx][ty + i];
}

// ---------------- GEMM: C[M][N] = A[M][K] * Bt[N][K]^T + bias, double-buffered ----------------
// MODE 0: bf16 -> [B,H,L,DH] (*oscale)   MODE 1: bf16 -> [B,H,DH,L]   MODE 2: fp32 [M][N]
constexpr int BM = 128, BN = 64, BK = 64;

template <int MODE>
__global__ __launch_bounds__(256) void gemm_bf16(
    const bf16* __restrict__ A, const bf16* __restrict__ Bt,
    const float* __restrict__ bias, void* __restrict__ outp, float oscale) {
  __shared__ bf16 As[2][BM * BK];   // 16KB each, XOR-swizzled rows (128B)
  __shared__ bf16 Bs[2][BN * BK];   // 8KB each
  const int tid = threadIdx.x;
  const int wid = tid >> 6, lane = tid & 63;
  const int lr = lane & 15, lg = lane >> 4;
  const int wr = wid >> 1, wc = wid & 1;  // 2x2 waves, wave tile 64x32

  // XCD-bijective block swizzle (nwg = 512, divisible by 8)
  const int bidf = blockIdx.y * gridDim.x + blockIdx.x;
  const int cpx = (gridDim.x * gridDim.y) >> 3;
  const int swz = (bidf & 7) * cpx + (bidf >> 3);
  const int n0 = (swz % gridDim.x) * BN, m0 = (swz / gridDim.x) * BM;

  f32x4 acc[4][2] = {};

  auto stage = [&](int bsel, int kt) {
#pragma unroll
    for (int i = 0; i < 4; ++i) {           // A: 16 x 1KB slots
      int slot = i * 4 + wid;
      int c = slot * 64 + lane;             // chunk 0..1023; row = c>>3, 8 chunks/row
      int row = c >> 3, cs = c & 7, g = cs ^ (row & 7);
      gload_lds16(A + (size_t)(m0 + row) * D_ + kt + g * 8, (char*)As[bsel] + slot * 1024);
    }
#pragma unroll
    for (int i = 0; i < 2; ++i) {           // B: 8 x 1KB slots
      int slot = i * 4 + wid;
      int c = slot * 64 + lane;
      int row = c >> 3, cs = c & 7, g = cs ^ (row & 7);
      gload_lds16(Bt + (size_t)(n0 + row) * D_ + kt + g * 8, (char*)Bs[bsel] + slot * 1024);
    }
  };

  stage(0, 0);
  for (int t = 0; t < D_ / BK; ++t) {
    const int cur = t & 1;
    if (t < D_ / BK - 1) {
      stage(cur ^ 1, (t + 1) * BK);
      asm volatile("s_waitcnt vmcnt(6)" ::: "memory");   // only cur's 6 must be done
    } else {
      asm volatile("s_waitcnt vmcnt(0)" ::: "memory");
    }
    block_bar();
#pragma unroll
    for (int kk = 0; kk < 2; ++kk) {
      bf16x8 af[4], bfr[2];
#pragma unroll
      for (int i = 0; i < 4; ++i) {
        int R = wr * 64 + i * 16 + lr;
        int ch = (kk * 4 + lg) ^ (R & 7);
        af[i] = *(const bf16x8*)((char*)As[cur] + R * 128 + ch * 16);
      }
#pragma unroll
      for (int j = 0; j < 2; ++j) {
        int R = wc * 32 + j * 16 + lr;
        int ch = (kk * 4 + lg) ^ (R & 7);
        bfr[j] = *(const bf16x8*)((char*)Bs[cur] + R * 128 + ch * 16);
      }
#pragma unroll
      for (int i = 0; i < 4; ++i)
#pragma unroll
        for (int j = 0; j < 2; ++j)
          acc[i][j] = __builtin_amdgcn_mfma_f32_16x16x32_bf16(af[i], bfr[j], acc[i][j], 0, 0, 0);
    }
    block_bar();
  }

  // epilogue: C/D layout col = lane&15, row = (lane>>4)*4 + r
#pragma unroll
  for (int i = 0; i < 4; ++i) {
#pragma unroll
    for (int j = 0; j < 2; ++j) {
      const int n = n0 + wc * 32 + j * 16 + lr;
      const float bn = bias[n];
      const int mbase = m0 + wr * 64 + i * 16 + lg * 4;
      if constexpr (MODE == 2) {
        float* out = (float*)outp;
#pragma unroll
        for (int r = 0; r < 4; ++r)
          out[(size_t)(mbase + r) * D_ + n] = acc[i][j][r] + bn;
      } else if constexpr (MODE == 0) {
        bf16* out = (bf16*)outp;
        const int h = n >> 6, dh = n & 63;
#pragma unroll
        for (int r = 0; r < 4; ++r) {
          int m = mbase + r;
          int b = m >> 11, l = m & (L_ - 1);
          out[((size_t)(b * H_ + h) * L_ + l) * DH_ + dh] = (bf16)((acc[i][j][r] + bn) * oscale);
        }
      } else {  // MODE 1: Vt[b][h][dh][l]
        bf16* out = (bf16*)outp;
        const int h = n >> 6, dh = n & 63;
        int b = mbase >> 11, l = mbase & (L_ - 1);
        bf16x4 pk;
#pragma unroll
        for (int r = 0; r < 4; ++r) pk[r] = (bf16)(acc[i][j][r] + bn);
        *(bf16x4*)(out + ((size_t)(b * H_ + h) * DH_ + dh) * L_ + l) = pk;
      }
    }
  }
}

// ---------------- flash attention (causal, paired q-tiles, double-buffered K/V) ----------------
// grid (32, H, B), block 128 (2 waves). Block x handles 32-row q-tiles {x, 63-x}.
// Q is pre-scaled by 0.125*log2e -> softmax in base-2 domain.
__global__ __launch_bounds__(128, 2) void attn_fwd(
    const bf16* __restrict__ Q,   // [B,H,L,DH], pre-scaled
    const bf16* __restrict__ K,   // [B,H,L,DH]
    const bf16* __restrict__ Vt,  // [B,H,DH,L]
    bf16* __restrict__ O) {       // [B,L,D]
  __shared__ bf16 Ks[2][64 * 64];   // 8KB per buf, XOR-swizzled 128B rows
  __shared__ bf16 Vs[2][64 * 64];
  __shared__ bf16 Ps[2][16 * 72];   // per-wave P strip (shared by both q-tiles)
  const int tid = threadIdx.x;
  const int wid = tid >> 6, lane = tid & 63;
  const int lr = lane & 15, lg = lane >> 4;
  const int x = blockIdx.x;
  const int h = blockIdx.y, b = blockIdx.z;
  const size_t bh = (size_t)b * H_ + h;
  const int qtA = x, qtB = 63 - x;
  const int qr0A = qtA * 32 + wid * 16, qr0B = qtB * 32 + wid * 16;
  const int ktmaxA = (qtA * 32 + 31) >> 6, ktmaxB = (qtB * 32 + 31) >> 6;

  bf16x8 qfA[2], qfB[2];
  {
    const bf16* qa = Q + (bh * L_ + qr0A) * DH_;
    const bf16* qb = Q + (bh * L_ + qr0B) * DH_;
#pragma unroll
    for (int kk = 0; kk < 2; ++kk) {
      qfA[kk] = *(const bf16x8*)(qa + lr * DH_ + kk * 32 + lg * 8);
      qfB[kk] = *(const bf16x8*)(qb + lr * DH_ + kk * 32 + lg * 8);
    }
  }

  f32x4 oA[4] = {}, oB[4] = {};
  float mA[4], lA[4], mB[4], lB[4];
#pragma unroll
  for (int r = 0; r < 4; ++r) { mA[r] = mB[r] = -3.0e38f; lA[r] = lB[r] = 0.f; }

  auto stage = [&](int bsel, int kt) {
    const bf16* kb = K + (bh * L_ + (size_t)kt * 64) * DH_;
    const bf16* vb = Vt + bh * (size_t)DH_ * L_ + (size_t)kt * 64;
#pragma unroll
    for (int i = 0; i < 4; ++i) {
      int slot = i * 2 + wid;              // 0..7 slots of 1KB
      int c = slot * 64 + lane;            // chunk 0..511, row = c>>3
      int row = c >> 3, cs = c & 7, g = cs ^ (row & 7);
      gload_lds16(kb + (size_t)row * DH_ + g * 8, (char*)Ks[bsel] + slot * 1024);
      gload_lds16(vb + (size_t)row * L_ + g * 8, (char*)Vs[bsel] + slot * 1024);
    }
  };

  bf16* pw = &Ps[wid][0];

  auto smx_pv = [&](f32x4* s, float* m, float* l, f32x4* o, int cur) {
    float t[4];
#pragma unroll
    for (int r = 0; r < 4; ++r)
      t[r] = fmaxf(fmaxf(s[0][r], s[1][r]), fmaxf(s[2][r], s[3][r]));
#pragma unroll
    for (int d = 1; d < 16; d <<= 1)
#pragma unroll
      for (int r = 0; r < 4; ++r) t[r] = fmaxf(t[r], __shfl_xor(t[r], d));
    bool need = false;
#pragma unroll
    for (int r = 0; r < 4; ++r) need |= (t[r] > m[r] + 11.0f);
    if (__any(need)) {  // defer-max: skip O-rescale when max barely grows
#pragma unroll
      for (int r = 0; r < 4; ++r) {
        float mn = fmaxf(m[r], t[r]);
        float c = exp2f(m[r] - mn);
        m[r] = mn; l[r] *= c;
#pragma unroll
        for (int j = 0; j < 4; ++j) o[j][r] *= c;
      }
    }
    float rs[4] = {0.f, 0.f, 0.f, 0.f};
#pragma unroll
    for (int j = 0; j < 4; ++j)
#pragma unroll
      for (int r = 0; r < 4; ++r) {
        float p = exp2f(s[j][r] - m[r]);
        s[j][r] = p;
        rs[r] += p;
      }
#pragma unroll
    for (int d = 1; d < 16; d <<= 1)
#pragma unroll
      for (int r = 0; r < 4; ++r) rs[r] += __shfl_xor(rs[r], d);
#pragma unroll
    for (int r = 0; r < 4; ++r) l[r] += rs[r];
    // P bounce through padded LDS strip (stride 72 el = 2-way max)
#pragma unroll
    for (int j = 0; j < 4; ++j)
#pragma unroll
      for (int r = 0; r < 4; ++r)
        pw[(lg * 4 + r) * 72 + j * 16 + lr] = (bf16)s[j][r];
    bf16x8 ap[2];
#pragma unroll
    for (int st = 0; st < 2; ++st)
      ap[st] = *(const bf16x8*)(pw + lr * 72 + st * 32 + lg * 8);
#pragma unroll
    for (int j = 0; j < 4; ++j)
#pragma unroll
      for (int st = 0; st < 2; ++st) {
        int dh = j * 16 + lr;
        int ch = (st * 4 + lg) ^ (dh & 7);
        bf16x8 bv = *(const bf16x8*)((char*)Vs[cur] + dh * 128 + ch * 16);
        o[j] = __builtin_amdgcn_mfma_f32_16x16x32_bf16(ap[st], bv, o[j], 0, 0, 0);
      }
  };

  stage(0, 0);
  for (int kt = 0; kt <= ktmaxB; ++kt) {
    const int cur = kt & 1;
    if (kt < ktmaxB) {
      stage(cur ^ 1, kt + 1);
      asm volatile("s_waitcnt vmcnt(8)" ::: "memory");
    } else {
      asm volatile("s_waitcnt vmcnt(0)" ::: "memory");
    }
    block_bar();
    const bool actA = (kt <= ktmaxA);

    f32x4 sB[4] = {}, sA[4] = {};
#pragma unroll
    for (int kk = 0; kk < 2; ++kk)
#pragma unroll
      for (int j = 0; j < 4; ++j) {
        int key = j * 16 + lr;
        int ch = (kk * 4 + lg) ^ (key & 7);
        bf16x8 bk = *(const bf16x8*)((char*)Ks[cur] + key * 128 + ch * 16);
        sB[j] = __builtin_amdgcn_mfma_f32_16x16x32_bf16(qfB[kk], bk, sB[j], 0, 0, 0);
        if (actA) sA[j] = __builtin_amdgcn_mfma_f32_16x16x32_bf16(qfA[kk], bk, sA[j], 0, 0, 0);
      }

    if (kt == ktmaxB) {
#pragma unroll
      for (int j = 0; j < 4; ++j) {
        int key = kt * 64 + j * 16 + lr;
#pragma unroll
        for (int r = 0; r < 4; ++r)
          if (key > qr0B + lg * 4 + r) sB[j][r] = -1.0e30f;
      }
    }
    if (actA && kt == ktmaxA) {
#pragma unroll
      for (int j = 0; j < 4; ++j) {
        int key = kt * 64 + j * 16 + lr;
#pragma unroll
        for (int r = 0; r < 4; ++r)
          if (key > qr0A + lg * 4 + r) sA[j][r] = -1.0e30f;
      }
    }

    smx_pv(sB, mB, lB, oB, cur);
    if (actA) smx_pv(sA, mA, lA, oA, cur);
    block_bar();
  }

  // epilogue
#pragma unroll
  for (int j = 0; j < 4; ++j)
#pragma unroll
    for (int r = 0; r < 4; ++r) {
      int dh = j * 16 + lr;
      O[((size_t)b * L_ + qr0A + lg * 4 + r) * D_ + h * DH_ + dh] = (bf16)(oA[j][r] / lA[r]);
      O[((size_t)b * L_ + qr0B + lg * 4 + r) * D_ + h * DH_ + dh] = (bf16)(oB[j][r] / lB[r]);
    }
}

// ---------------- launcher ----------------
extern "C" void kernel_launch(void* const* d_in, const int* in_sizes, int n_in,
                              void* d_out, int out_size, void* d_ws, size_t ws_size,
                              hipStream_t stream) {
  const float* q  = (const float*)d_in[0];
  const float* k  = (const float*)d_in[1];
  const float* v  = (const float*)d_in[2];
  const float* Wq = (const float*)d_in[4];
  const float* bq = (const float*)d_in[5];
  const float* Wk = (const float*)d_in[6];
  const float* bk = (const float*)d_in[7];
  const float* Wv = (const float*)d_in[8];
  const float* bv = (const float*)d_in[9];
  const float* Wo = (const float*)d_in[10];
  const float* bo = (const float*)d_in[11];

  // ws layout (peak 40MB via aliasing):
  // [0,8): castQ -> later attn O      [8,16): castK -> later Qb
  // [16,24): castV -> later Kb        [24,32): WT (WqT,WkT,WvT,WoT)
  // [32,40): Vtb
  char* ws = (char*)d_ws;
  bf16* castQ = (bf16*)ws;
  bf16* castK = (bf16*)(ws + (8ull << 20));
  bf16* castV = (bf16*)(ws + (16ull << 20));
  bf16* WT    = (bf16*)(ws + (24ull << 20));
  bf16* Vtb   = (bf16*)(ws + (32ull << 20));
  bf16* Kb    = (bf16*)(ws + (16ull << 20));  // over castV (dead after V-GEMM)
  bf16* Qb    = (bf16*)(ws + (8ull << 20));   // over castK (dead after K-GEMM)
  bf16* Ob    = (bf16*)ws;                    // over castQ (dead after Q-GEMM)

  transpose_cast_w<<<dim3(32, 32, 4), dim3(32, 8), 0, stream>>>(Wq, Wk, Wv, Wo, WT);
  cast3<<<dim3((M_ * D_ / 4) / 256, 3), 256, 0, stream>>>(q, k, v, castQ);

  dim3 gg(D_ / BN, M_ / BM);  // (16, 32) = 512 blocks
  gemm_bf16<1><<<gg, 256, 0, stream>>>(castV, WT + 2ull * D_ * D_, bv, Vtb, 1.0f);
  gemm_bf16<0><<<gg, 256, 0, stream>>>(castK, WT + 1ull * D_ * D_, bk, Kb, 1.0f);
  gemm_bf16<0><<<gg, 256, 0, stream>>>(castQ, WT, bq, Qb, QSCALE);

  attn_fwd<<<dim3(32, H_, B_), 128, 0, stream>>>(Qb, Kb, Vtb, Ob);

  gemm_bf16<2><<<gg, 256, 0, stream>>>(Ob, WT + 3ull * D_ * D_, bo, (float*)d_out, 1.0f);
}